// Round 10
// baseline (145.464 us; speedup 1.0000x reference)
//
#include <hip/hip_runtime.h>

#define KTAG 52
#define START_TAG 50
#define STOP_TAG 51
#define TMAX 512
#define NCU 256

__device__ __forceinline__ float rdlanef(float v, int l) {
    return __int_as_float(__builtin_amdgcn_readlane(__float_as_int(v), l));
}

// matvec with 4-deep software-pipelined readlane broadcast:
// rd for j+4..j+7 issued BEFORE fmas of j..j+3 -> every rd->fma distance >= 4
// instructions, covering the ~8-10 cy readlane result latency.
__device__ __forceinline__ float matv(const float* __restrict__ E, float x) {
    float a0 = 0.f, a1 = 0.f, a2 = 0.f, a3 = 0.f;
    float s0 = rdlanef(x, 0), s1 = rdlanef(x, 1),
          s2 = rdlanef(x, 2), s3 = rdlanef(x, 3);
    #pragma unroll
    for (int j = 0; j < 48; j += 4) {
        float t0 = rdlanef(x, j + 4), t1 = rdlanef(x, j + 5),
              t2 = rdlanef(x, j + 6), t3 = rdlanef(x, j + 7);
        a0 = fmaf(E[j + 0], s0, a0);
        a1 = fmaf(E[j + 1], s1, a1);
        a2 = fmaf(E[j + 2], s2, a2);
        a3 = fmaf(E[j + 3], s3, a3);
        s0 = t0; s1 = t1; s2 = t2; s3 = t3;
    }
    a0 = fmaf(E[48], s0, a0);
    a1 = fmaf(E[49], s1, a1);
    a2 = fmaf(E[50], s2, a2);
    a3 = fmaf(E[51], s3, a3);
    return (a0 + a1) + (a2 + a3);
}

// Scaled linear-domain chain, NO LDS inside (readlane broadcast only).
// FWD:  beta' = matv(E, beta) * e_t        BWD:  beta' = matv(E^T, beta * e_t)
template<bool BWD>
__device__ __forceinline__ float chain(const float* __restrict__ p0, int stride,
                                       int maxk, int nsteps, const float* __restrict__ Erow,
                                       float beta, float& M2) {
    constexpr float L2E = 1.4426950408889634f;
    M2 = 0.f;

    auto lgt = [&](int k) -> float {
        int kc = k < maxk ? k : maxk;          // clamped prefetch, always in-bounds
        return p0[(long)stride * kc];
    };
    auto STEP = [&](float lg, float scl) {
        float e = exp2f(lg * L2E);
        if (BWD) beta = matv(Erow, beta * e * scl);
        else     beta = matv(Erow, beta * scl) * e;
    };

    float l0 = lgt(0), l1 = lgt(1), l2 = lgt(2), l3 = lgt(3);
    int k = 0;
    while (k + 4 <= nsteps) {
        float n0 = lgt(k+4), n1 = lgt(k+5), n2 = lgt(k+6), n3 = lgt(k+7);
        float scl = 1.f;
        if (k > 0) {                            // uniform; beta[0] > 0 once started
            float m = fmaxf(rdlanef(beta, 0), 1e-30f);
            M2 += log2f(m);
            scl = 1.f / m;
        }
        STEP(l0, scl); STEP(l1, 1.f); STEP(l2, 1.f); STEP(l3, 1.f);
        l0 = n0; l1 = n1; l2 = n2; l3 = n3;
        k += 4;
    }
    if (k < nsteps) {
        float scl = 1.f;
        if (k > 0) {
            float m = fmaxf(rdlanef(beta, 0), 1e-30f);
            M2 += log2f(m);
            scl = 1.f / m;
        }
        STEP(l0, scl); ++k;
        if (k < nsteps) { STEP(l1, 1.f); ++k; }
        if (k < nsteps) { STEP(l2, 1.f); ++k; }
    }
    return beta;
}

// ---- Deterministic length-rank: perm[rank] = b (ascending len, idx tiebreak)
#define LPL 16
__global__ __launch_bounds__(64) void rank_kernel(
    const int* __restrict__ lens, int* __restrict__ perm, int B)
{
    const int lane = threadIdx.x;
    int myl[LPL];
    #pragma unroll
    for (int k = 0; k < LPL; ++k) {
        int j = lane * LPL + k;
        myl[k] = (j < B) ? lens[j] : 0x7fffffff;
    }
    const int base = blockIdx.x * 64;
    const int Lme = (base + lane < B) ? lens[base + lane] : 0x7fffffff;
    for (int i = 0; i < 64; ++i) {
        int b = base + i;
        if (b >= B) break;
        int Lb = __shfl(Lme, i);               // broadcast, no global load
        int r = 0;
        #pragma unroll
        for (int k = 0; k < LPL; ++k) {
            int j = lane * LPL + k;
            r += (myl[k] < Lb || (myl[k] == Lb && j < b)) ? 1 : 0;
        }
        #pragma unroll
        for (int off = 32; off; off >>= 1) r += __shfl_xor(r, off);
        if (lane == 0) perm[r] = b;
    }
}

// One block (2 waves) per batch: wave0 fwd half, wave1 bwd half; combine after
// ONE barrier (outside all loops). CU q's four co-resident blocks
// {q, q+256, q+512, q+768} map to ranks {4q..4q+3}: all four batches have
// SIMILAR length, so each SIMD keeps 2 equal-length waves alive to the end
// (TLP fills readlane-latency stalls; no solo tails).
__global__ __launch_bounds__(128, 1) void crf_split_kernel(
    const float* __restrict__ logits,   // [B, T, K]
    const float* __restrict__ trans,    // [K, K]
    const int*   __restrict__ labels,   // [B, T]
    const int*   __restrict__ lens,     // [B]
    const int*   __restrict__ perm,     // [B]
    float* __restrict__ out, int B)
{
    constexpr float L2E = 1.4426950408889634f;
    constexpr float LN2 = 0.6931471805599453f;

    const int blk  = blockIdx.x;
    const int wave = threadIdx.x >> 6;
    const int lane = threadIdx.x & 63;
    const bool active = lane < KTAG;
    const bool bwd = (wave == 1);

    int r = blk;
    if (B == 4 * NCU) {
        int q = blk & (NCU - 1), j = blk >> 8;
        r = 4 * q + j;                      // similar-length quad per CU
    }
    const int batch = perm[r];
    const int len = lens[batch];
    const int mid = len >> 1;               // fwd steps; bwd = len - mid >= 1

    // E row: wave0 = exp(trans[lane][j]) (row), wave1 = exp(trans[j][lane]) (col)
    float Erow[KTAG];
    #pragma unroll
    for (int j = 0; j < KTAG; ++j) {
        float tv = active ? (bwd ? trans[j * KTAG + lane]
                                 : trans[(size_t)lane * KTAG + j]) : 0.f;
        Erow[j] = active ? exp2f(tv * L2E) : 0.f;
    }

    const float* base = logits + (size_t)batch * TMAX * KTAG + (active ? lane : 0);

    __shared__ __align__(16) float sB[64];
    __shared__ float sM2f, sEm, sTr;

    float M2, beta;
    if (bwd) {
        float b0 = active ? exp2f(trans[STOP_TAG * KTAG + lane] * L2E) : 0.f;
        beta = chain<true>(base + (size_t)(len - 1) * KTAG, -KTAG,
                           len - 1, len - mid, Erow, b0, M2);
    } else {
        float b0 = (lane == START_TAG) ? 1.f : 0.f;
        beta = chain<false>(base, KTAG, TMAX - 1, mid, Erow, b0, M2);

        // gold-path scores on the (shorter) fwd wave; batched independent loads
        const int*   labp = labels + (size_t)batch * TMAX;
        const float* lgb  = logits + (size_t)batch * TMAX * KTAG;
        int lab[8], prv[8]; bool msk[8];
        #pragma unroll
        for (int c = 0; c < 8; ++c) {
            int tt = c * 64 + lane;
            msk[c] = tt < len;
            int ttc = msk[c] ? tt : 0;
            lab[c] = labp[ttc];
            prv[c] = (ttc == 0) ? START_TAG : labp[ttc - 1];
        }
        float em = 0.f, tr = 0.f;
        #pragma unroll
        for (int c = 0; c < 8; ++c) {
            int ttc = msk[c] ? (c * 64 + lane) : 0;
            float ev = lgb[(size_t)ttc * KTAG + lab[c]];
            float tv = trans[lab[c] * KTAG + prv[c]];
            if (msk[c]) { em += ev; tr += tv; }
        }
        if (lane == 0) tr += trans[STOP_TAG * KTAG + labp[len - 1]];
        #pragma unroll
        for (int off = 32; off; off >>= 1) {
            em += __shfl_xor(em, off);
            tr += __shfl_xor(tr, off);
        }
        sB[lane] = beta;
        if (lane == 0) { sM2f = M2; sEm = em; sTr = tr; }
    }
    __syncthreads();                        // single barrier, outside all loops

    if (bwd) {
        // Z = gamma^T beta_mid
        float d = beta * sB[lane];
        #pragma unroll
        for (int off = 32; off; off >>= 1) d += __shfl_xor(d, off);
        float partition = LN2 * (sM2f + M2 + log2f(d));
        if (lane == 0) out[batch] = partition + sEm - sTr;
    }
}

extern "C" void kernel_launch(void* const* d_in, const int* in_sizes, int n_in,
                              void* d_out, int out_size, void* d_ws, size_t ws_size,
                              hipStream_t stream) {
    const float* logits = (const float*)d_in[0];
    const float* trans  = (const float*)d_in[1];
    const int*   labels = (const int*)d_in[2];
    const int*   lens   = (const int*)d_in[3];
    float* out = (float*)d_out;

    const int B = in_sizes[3];
    int* perm = (int*)d_ws;

    rank_kernel<<<dim3((B + 63) / 64), dim3(64), 0, stream>>>(lens, perm, B);
    crf_split_kernel<<<dim3(B), dim3(128), 0, stream>>>(
        logits, trans, labels, lens, perm, out, B);
}